// Round 3
// baseline (883.308 us; speedup 1.0000x reference)
//
#include <hip/hip_runtime.h>
#include <math.h>

#define NB 4
#define NW 24
#define H 512
#define H2 1024
#define H5 2560
#define NCELL 300   // n*(n+1)/2 valid cells per batch
#define NEED_BYTES ((size_t)72<<20)

// Private fallback workspace: allocated ONCE at library load (outside
// kernel_launch, so graph capture never sees the hipMalloc).
static float* g_buf = nullptr;
__attribute__((constructor)) static void dio_alloc_ws(){
  (void)hipMalloc((void**)&g_buf, NEED_BYTES);
}

typedef __attribute__((ext_vector_type(8))) short bf16x8;   // 8 bf16 (4 VGPRs)
typedef __attribute__((ext_vector_type(4))) float f32x4;
typedef unsigned short ushort_t;
typedef unsigned long long u64_t;

__device__ __forceinline__ int coff(int l){ return l*NW - (l*(l-1))/2; }
__device__ __forceinline__ float sigm(float x){ return 1.f/(1.f+__expf(-x)); }
__device__ __forceinline__ float ftanh(float x){ return 1.f - 2.f/(__expf(2.f*x)+1.f); }

__device__ __forceinline__ ushort_t f2b(float x){  // fp32 -> bf16 RNE
  unsigned int u = __float_as_uint(x);
  u += 0x7FFF + ((u>>16)&1);
  return (ushort_t)(u>>16);
}
__device__ __forceinline__ float b2f(ushort_t h){
  return __uint_as_float(((unsigned int)h)<<16);
}
// split-bf16: x ~= hi + lo with effective ~2^-17 relative error
__device__ __forceinline__ void split_store(ushort_t* __restrict__ ph,
                                            ushort_t* __restrict__ pl,
                                            size_t idx, float x){
  ushort_t h = f2b(x);
  ph[idx] = h;
  pl[idx] = f2b(x - b2f(h));
}

// 16B A-fragment load via two agent-scope relaxed atomic loads: reads at the
// coherence point (MALL), so same-dispatch producer data (written with
// agent-scope atomic stores) is visible without any cache invalidation.
__device__ __forceinline__ bf16x8 ld_frag_agent(const ushort_t* p){
  u64_t a = __hip_atomic_load((u64_t*)p,     __ATOMIC_RELAXED, __HIP_MEMORY_SCOPE_AGENT);
  u64_t b = __hip_atomic_load((u64_t*)p + 1, __ATOMIC_RELAXED, __HIP_MEMORY_SCOPE_AGENT);
  union { u64_t q[2]; bf16x8 v; } u;
  u.q[0] = a; u.q[1] = b;
  return u.v;
}

// full-wave dot: compat(lc,rc) = U[lc].[H(rc);C(rc)] + S[lc] + S[rc]
__device__ __forceinline__ float compat_dot(const float* __restrict__ cU,
                                            const float* __restrict__ cH,
                                            const float* __restrict__ cC,
                                            const float* __restrict__ cS,
                                            int lc, int rc, int lane){
  const float4* U4  = (const float4*)(cU + (size_t)lc*H2);
  const float4* Hr4 = (const float4*)(cH + (size_t)rc*H);
  const float4* Cr4 = (const float4*)(cC + (size_t)rc*H);
  float p = 0.f;
  #pragma unroll
  for (int it=0; it<2; it++){
    float4 u = U4[lane + 64*it], h = Hr4[lane + 64*it];
    p += u.x*h.x + u.y*h.y + u.z*h.z + u.w*h.w;
  }
  #pragma unroll
  for (int it=0; it<2; it++){
    float4 u = U4[128 + lane + 64*it], c = Cr4[lane + 64*it];
    p += u.x*c.x + u.y*c.y + u.z*c.z + u.w*c.w;
  }
  #pragma unroll
  for (int off=32; off>0; off>>=1) p += __shfl_down(p, off);
  return p + cS[lc] + cS[rc];
}

// ---- merged init: split Wi/Ws, transpose+split Wbil, leaves, flag zero
__global__ void k_init(const float* __restrict__ seqt,
                       const float* __restrict__ Wi, const float* __restrict__ Ws,
                       const float* __restrict__ Wbil,
                       ushort_t* __restrict__ WiBh, ushort_t* __restrict__ WiBl,
                       ushort_t* __restrict__ WsBh, ushort_t* __restrict__ WsBl,
                       ushort_t* __restrict__ WbilTh, ushort_t* __restrict__ WbilTl,
                       float* __restrict__ cH, float* __restrict__ cC, float* __restrict__ cS,
                       ushort_t* __restrict__ cHbh, ushort_t* __restrict__ cHbl,
                       ushort_t* __restrict__ cCbh, ushort_t* __restrict__ cCbl,
                       unsigned* __restrict__ flags){
  const int blk = blockIdx.x, t = threadIdx.x;
  if (blk < 10240){                       // Wi/Ws split (2*H5*H elems exactly)
    int i = blk*256 + t;
    const int n = H5*H;
    if (i < n) split_store(WiBh, WiBl, i, Wi[i]);
    else       split_store(WsBh, WsBl, i-n, Ws[i-n]);
  } else if (blk < 11264){                // Wbil transpose+split (1024 tiles)
    __shared__ float tile[32][33];
    int tb = blk - 10240;
    int tr = (tb>>5)*32, tc = (tb&31)*32;
    int tx = t & 31, ty = t >> 5;         // 32 x 8
    #pragma unroll
    for (int i=0;i<32;i+=8)
      tile[ty+i][tx] = Wbil[(size_t)(tr+ty+i)*H2 + tc+tx];
    __syncthreads();
    #pragma unroll
    for (int i=0;i<32;i+=8)
      split_store(WbilTh, WbilTl, (size_t)(tc+ty+i)*H2 + tr+tx, tile[tx][ty+i]);
  } else if (blk < 11456){                // leaves (192 blocks)
    int tid = (blk-11264)*256 + t;
    if (tid < NB*NW*H){
      int b = tid/(NW*H); int r = tid%(NW*H); int i = r/H; int d = r%H;
      size_t idx = (size_t)(b*NCELL + i)*H + d;     // coff(0)==0
      float hv = seqt[(size_t)(b*NW+i)*H2 + d];
      float cv = seqt[(size_t)(b*NW+i)*H2 + H + d];
      cH[idx]=hv; cC[idx]=cv;
      split_store(cHbh,cHbl,idx,hv);
      split_store(cCbh,cCbl,idx,cv);
      if (d==0) cS[b*NCELL+i] = 0.f;
    }
  } else {                                // flag zero (24 diagonals x 128)
    for (int i=t; i<NW*128; i+=256) flags[i] = 0u;
  }
}

__device__ __forceinline__ void mfma3(f32x4& acc, bf16x8 ah, bf16x8 al,
                                      bf16x8 bh, bf16x8 bl){
  // split product; lo*lo (~2^-34 rel) dropped
  acc = __builtin_amdgcn_mfma_f32_16x16x32_bf16(ah, bh, acc, 0,0,0);
  acc = __builtin_amdgcn_mfma_f32_16x16x32_bf16(ah, bl, acc, 0,0,0);
  acc = __builtin_amdgcn_mfma_f32_16x16x32_bf16(al, bh, acc, 0,0,0);
}

// ---- fused stage for diagonal L: combine diag L (1 block/cell) + compat
// writers for diag L+1 + MFMA projection of diag L (384 j-tile blocks).
// Intra-dispatch dependency (combine -> proj) handled by per-cell flags:
// combine publishes bf16 charts with relaxed AGENT atomic stores (write at
// coherence point, no dirty L2, no fences) then bumps the cell flag; proj
// spins on flags and reads A-fragments with agent atomic loads. Everything
// crossing a dispatch boundary uses regular loads/stores (runtime flush).
// Deadlock-free: 72.5KB LDS -> 2 blocks/CU = 512 slots >= worst-case mix;
// combine blocks (low blockIdx, <=92) always fit.
__global__ void __launch_bounds__(512)
k_stage(const ushort_t* __restrict__ WiBh, const ushort_t* __restrict__ WiBl,
        const ushort_t* __restrict__ WsBh, const ushort_t* __restrict__ WsBl,
        const ushort_t* __restrict__ WbilTh, const ushort_t* __restrict__ WbilTl,
        const float* __restrict__ bi, const float* __restrict__ bs,
        ushort_t* cHbh, ushort_t* cHbl, ushort_t* cCbh, ushort_t* cCbl,
        float* __restrict__ cPI, float* __restrict__ cPS, float* __restrict__ cU,
        float* __restrict__ cH, float* __restrict__ cC, float* __restrict__ cS,
        const float* __restrict__ compatR, float* __restrict__ compatW,
        unsigned* flags, float* __restrict__ out, int L)
{
  __shared__ __attribute__((aligned(16))) ushort_t wlds[32768];  // 64 KB
  __shared__ f32x4 red[8][64];                                   // 8 KB
  __shared__ float compat_s[32];
  __shared__ float wts_s[32];

  const int P = NW - L;
  const int ncomb = (L>=1) ? NB*P : 0;
  const int P1 = P-1, nterm = L-1;
  const int nwt = (L>=1 && P1>0 && nterm>0) ? NB*P1*nterm : 0;
  const int wblkN = (nwt+7)>>3;
  const int t = threadIdx.x, wave = t>>6, lane = t&63;
  unsigned* flagD = flags + L*128;
  int blk = blockIdx.x;

  // ================= role A: combine one cell of diagonal L ================
  if (blk < ncomb){
    const int b = blk / P, left = blk % P;
    // phase 1: boundary compat inline (waves 4,5); interior precomputed
    if (wave == 4){
      int lc = b*NCELL + left;                       // (left,0) leaf
      int rc = b*NCELL + coff(L-1) + left+1;
      float v = compat_dot(cU, cH, cC, cS, lc, rc, lane);
      if (lane==0) compat_s[0] = v;
    } else if (wave == 5 && L >= 2){
      int lc = b*NCELL + coff(L-1) + left;
      int rc = b*NCELL + left+L;                     // (left+L,0) leaf
      float v = compat_dot(cU, cH, cC, cS, lc, rc, lane);
      if (lane==0) compat_s[L-1] = v;
    }
    if (t >= 1 && t <= L-2) compat_s[t] = compatR[(b*NW + left)*NW + t];
    __syncthreads();
    const size_t nc = (size_t)(b*NCELL + coff(L) + left);
    // phase 2: softmax over k (serial on t0, order-identical to before)
    if (t==0){
      float mx = -1e30f;
      for (int k=0;k<L;k++) mx = fmaxf(mx, compat_s[k]);
      float den = 0.f;
      for (int k=0;k<L;k++){ float e = __expf(compat_s[k]-mx); wts_s[k]=e; den+=e; }
      float inv = 1.f/den, S = 0.f;
      for (int k=0;k<L;k++){ wts_s[k]*=inv; S += wts_s[k]*compat_s[k]; }
      if (L < NW-1) cS[nc] = S;
    }
    __syncthreads();
    // phase 3: thread owns dim=t. Residue partials q8=0..7 summed in the
    // SAME order as the old 8-way kpar split -> bit-exact.
    const int dim = t;
    float aH = 0.f, aC = 0.f;
    for (int q8=0; q8<8; q8++){
      float sH = 0.f, sC = 0.f;
      for (int k=q8; k<L; k+=8){
        float wk = wts_s[k];
        int lc = b*NCELL + coff(k) + left;
        int rc = b*NCELL + coff(L-1-k) + left+k+1;
        const float* PI = cPI + (size_t)lc*H5;
        const float* PS = cPS + (size_t)rc*H5;
        float p0 = PI[dim]     + PS[dim];
        float p1 = PI[H+dim]   + PS[H+dim];
        float p2 = PI[2*H+dim] + PS[2*H+dim];
        float p3 = PI[3*H+dim] + PS[3*H+dim];
        float p4 = PI[4*H+dim] + PS[4*H+dim];
        float lcv = cC[(size_t)lc*H + dim];
        float rcv = cC[(size_t)rc*H + dim];
        float mem = sigm(p1)*lcv + sigm(p2)*rcv + sigm(p0)*ftanh(p3);
        float h = sigm(p4)*ftanh(mem);
        sH += wk*h; sC += wk*mem;
      }
      aH += sH; aC += sC;
    }
    if (L == NW-1){                        // root: write output directly
      out[b*H2 + dim]     = aH;
      out[b*H2 + H + dim] = aC;
      return;
    }
    cH[nc*H + dim] = aH;                   // regular: consumed next dispatch
    cC[nc*H + dim] = aC;
    // bf16 splits for same-dispatch proj: packed pairs, agent atomic stores
    ushort_t hH = f2b(aH), lH = f2b(aH - b2f(hH));
    ushort_t hC = f2b(aC), lC = f2b(aC - b2f(hC));
    unsigned nh = (unsigned)__shfl_down((int)hH, 1);
    unsigned nl = (unsigned)__shfl_down((int)lH, 1);
    unsigned mh = (unsigned)__shfl_down((int)hC, 1);
    unsigned ml = (unsigned)__shfl_down((int)lC, 1);
    if (!(t & 1)){
      const size_t pi = (nc*H + dim) >> 1;
      __hip_atomic_store((unsigned*)cHbh + pi, (unsigned)hH | (nh<<16),
                         __ATOMIC_RELAXED, __HIP_MEMORY_SCOPE_AGENT);
      __hip_atomic_store((unsigned*)cHbl + pi, (unsigned)lH | (nl<<16),
                         __ATOMIC_RELAXED, __HIP_MEMORY_SCOPE_AGENT);
      __hip_atomic_store((unsigned*)cCbh + pi, (unsigned)hC | (mh<<16),
                         __ATOMIC_RELAXED, __HIP_MEMORY_SCOPE_AGENT);
      __hip_atomic_store((unsigned*)cCbl + pi, (unsigned)lC | (ml<<16),
                         __ATOMIC_RELAXED, __HIP_MEMORY_SCOPE_AGENT);
    }
    __syncthreads();    // drains each wave's vmcnt before barrier release
    if (t == 0)
      __hip_atomic_fetch_add(flagD + b*32 + left, 1u,
                             __ATOMIC_RELAXED, __HIP_MEMORY_SCOPE_AGENT);
    return;
  }
  blk -= ncomb;

  // ========= role B: compat writers for diag L+1 (reads diag <= L-1) =======
  if (blk < wblkN){
    const int tid8 = blk*8 + wave;
    if (tid8 < nwt){
      int cell1 = tid8 / nterm;
      int k = 1 + tid8 % nterm;
      int b = cell1 / P1, left = cell1 % P1;
      int lc = b*NCELL + coff(k) + left;
      int rc = b*NCELL + coff(L-k) + left+k+1;
      float v = compat_dot(cU, cH, cC, cS, lc, rc, lane);
      if (lane==0) compatW[(b*NW + left)*NW + k] = v;
    }
    return;
  }
  blk -= wblkN;

  // ================= role C: MFMA projection of diagonal L =================
  const int jt = blk;          // 0-159: PI, 160-319: PS, 320-383: U
  const int r = lane & 15;     // A row (m) / B row (j) / D col
  const int q = lane >> 4;     // quad: k = q*8 + i

  int kind, j0;
  if (jt < 160){ kind=0; j0 = jt*16; }
  else if (jt < 320){ kind=1; j0 = (jt-160)*16; }
  else { kind=2; j0 = (jt-320)*16; }

  // stage weights into LDS (once per dispatch; overlaps combine's compute)
  char* wb = (char*)wlds;
  if (kind < 2){
    const ushort_t* srcH = (kind==0 ? WiBh : WsBh) + (size_t)j0*H;
    const ushort_t* srcL = (kind==0 ? WiBl : WsBl) + (size_t)j0*H;
    #pragma unroll
    for (int e = t; e < 1024; e += 512){          // 16 rows x 64 16B-chunks
      const int row = e >> 6, c0 = (e & 63) << 3;
      bf16x8 vh = *(const bf16x8*)(srcH + (size_t)row*H + c0);
      bf16x8 vl = *(const bf16x8*)(srcL + (size_t)row*H + c0);
      const int off = ((row<<10) + (c0<<1)) ^ ((row&7)<<4);
      *(bf16x8*)(wb + off) = vh;
      *(bf16x8*)(wb + 16384 + off) = vl;
    }
  } else {
    const ushort_t* srcH = WbilTh + (size_t)j0*H2;
    const ushort_t* srcL = WbilTl + (size_t)j0*H2;
    #pragma unroll
    for (int e = t; e < 2048; e += 512){          // 16 rows x 128 chunks
      const int row = e >> 7, c0 = (e & 127) << 3;
      bf16x8 vh = *(const bf16x8*)(srcH + (size_t)row*H2 + c0);
      bf16x8 vl = *(const bf16x8*)(srcL + (size_t)row*H2 + c0);
      const int off = ((row<<11) + (c0<<1)) ^ ((row&7)<<4);
      *(bf16x8*)(wb + off) = vh;
      *(bf16x8*)(wb + 32768 + off) = vl;
    }
  }
  __syncthreads();

  const int Mtot = NB*P, mt = (Mtot+15)>>4;
  const int swz = (r&7)<<4;
  const int jo = j0 + r;
  float bias = 0.f;
  if (kind==0) bias = bi[jo] + ((jo>=H && jo<3*H)?1.f:0.f);   // ins_bias on [H,3H)
  else if (kind==1) bias = bs[jo];

  const f32x4 z4 = {0.f,0.f,0.f,0.f};
  const int units = 2*mt;                 // (m-tile, K-half) pairs
  const int rounds = (units + 7) >> 3;
  for (int rd = 0; rd < rounds; rd++){
    // wait for this round's cells (combine blocks of this dispatch)
    if (L >= 1){
      const int c0 = rd*64;
      const int c1 = min(Mtot, c0+64);
      if (t < c1 - c0){
        const int mg = c0 + t;
        unsigned* f = flagD + (mg/P)*32 + (mg%P);
        while (__hip_atomic_load(f, __ATOMIC_RELAXED, __HIP_MEMORY_SCOPE_AGENT) == 0u)
          __builtin_amdgcn_s_sleep(2);
      }
      __syncthreads();
    }
    const int u = rd*8 + wave;
    const int half = u & 1;               // wave parity (rd*8 even)
    const int mtile = u >> 1;
    f32x4 sA = z4;
    int m0 = 0, nm = 0;
    if (u < units){
      m0 = mtile*16;
      nm = min(16, Mtot - m0);
      const int mg = m0 + (r < nm ? r : 0);
      const size_t arow = (size_t)((mg/P)*NCELL + coff(L) + mg%P)*H;
      f32x4 acc[4];
      #pragma unroll
      for (int wi=0;wi<4;wi++) acc[wi] = z4;
      if (kind < 2){
        #pragma unroll
        for (int wi=0; wi<4; wi++){
          const int w = half*4 + wi;      // chain id 0..7
          #pragma unroll
          for (int s=0;s<2;s++){
            const int ko = w*64 + q*8 + s*32;
            bf16x8 ah = ld_frag_agent(cHbh + arow + ko);
            bf16x8 al = ld_frag_agent(cHbl + arow + ko);
            const int bo = ((r<<10) + (ko<<1)) ^ swz;
            bf16x8 bh = *(const bf16x8*)(wb + bo);
            bf16x8 bl = *(const bf16x8*)(wb + 16384 + bo);
            mfma3(acc[wi], ah, al, bh, bl);
          }
        }
      } else {
        // U: chains 0-3 -> H chart, 4-7 -> C chart; global k = w*128 + ...
        const ushort_t* ah_ = (half==0 ? cHbh : cCbh) + arow;
        const ushort_t* al_ = (half==0 ? cHbl : cCbl) + arow;
        #pragma unroll
        for (int wi=0; wi<4; wi++){
          const int w = half*4 + wi;
          const int kg0 = w*128, ka0 = kg0 & 511;
          #pragma unroll
          for (int s=0;s<4;s++){
            const int so = s*32 + q*8;
            bf16x8 ah = ld_frag_agent(ah_ + ka0 + so);
            bf16x8 al = ld_frag_agent(al_ + ka0 + so);
            const int bo = ((r<<11) + ((kg0+so)<<1)) ^ swz;
            bf16x8 bh = *(const bf16x8*)(wb + bo);
            bf16x8 bl = *(const bf16x8*)(wb + 32768 + bo);
            mfma3(acc[wi], ah, al, bh, bl);
          }
        }
      }
      sA = (acc[0]+acc[1]) + (acc[2]+acc[3]);   // half-subtree, fixed order
    }
    red[wave][lane] = sA;
    __syncthreads();
    if (half==0 && u < units){
      f32x4 tot = red[wave][lane] + red[wave|1][lane]; // ((0+1)+(2+3))+((4+5)+(6+7))
      #pragma unroll
      for (int reg=0; reg<4; reg++){
        const int m = q*4 + reg;
        if (m < nm){
          const int mg2 = m0 + m;
          const size_t cell = (size_t)((mg2/P)*NCELL + coff(L) + mg2%P);
          const float v = tot[reg];
          if (kind==0)      cPI[cell*H5 + jo] = v + bias;
          else if (kind==1) cPS[cell*H5 + jo] = v + bias;
          else              cU [cell*H2 + jo] = v;
        }
      }
    }
    __syncthreads();   // red reused next round
  }
}

extern "C" void kernel_launch(void* const* d_in, const int* in_sizes, int n_in,
                              void* d_out, int out_size, void* d_ws, size_t ws_size,
                              hipStream_t stream){
  const float* seqt = (const float*)d_in[0];
  const float* Wi   = (const float*)d_in[1];
  const float* bi   = (const float*)d_in[2];
  const float* Ws   = (const float*)d_in[3];
  const float* bs   = (const float*)d_in[4];
  const float* Wbil = (const float*)d_in[5];
  float* out = (float*)d_out;

  float* p = (ws_size >= NEED_BYTES && g_buf == nullptr) ? (float*)d_ws : g_buf;
  float* cH  = p; p += (size_t)NB*NCELL*H;
  float* cC  = p; p += (size_t)NB*NCELL*H;
  float* cS  = p; p += (size_t)NB*NCELL;
  float* cPI = p; p += (size_t)NB*NCELL*H5;
  float* cPS = p; p += (size_t)NB*NCELL*H5;
  float* cU  = p; p += (size_t)NB*NCELL*H2;
  float* compatA = p; p += (size_t)NB*NW*NW;
  float* compatB = p; p += (size_t)NB*NW*NW;
  ushort_t* u = (ushort_t*)p;
  ushort_t* WiBh   = u; u += (size_t)H5*H;
  ushort_t* WiBl   = u; u += (size_t)H5*H;
  ushort_t* WsBh   = u; u += (size_t)H5*H;
  ushort_t* WsBl   = u; u += (size_t)H5*H;
  ushort_t* WbilTh = u; u += (size_t)H2*H2;
  ushort_t* WbilTl = u; u += (size_t)H2*H2;
  ushort_t* cHbh   = u; u += (size_t)NB*NCELL*H;
  ushort_t* cHbl   = u; u += (size_t)NB*NCELL*H;
  ushort_t* cCbh   = u; u += (size_t)NB*NCELL*H;
  ushort_t* cCbl   = u; u += (size_t)NB*NCELL*H;
  unsigned* flags  = (unsigned*)u;   // NW*128 u32 (4B-aligned: even ushorts)

  k_init<<<11457, 256, 0, stream>>>(seqt, Wi, Ws, Wbil,
      WiBh, WiBl, WsBh, WsBl, WbilTh, WbilTl,
      cH, cC, cS, cHbh, cHbl, cCbh, cCbl, flags);

  for (int L=0; L<NW; L++){
    int P = NW - L;
    int ncomb = (L>=1) ? NB*P : 0;
    int P1 = P-1, nterm = L-1;
    int nwt = (L>=1 && P1>0 && nterm>0) ? NB*P1*nterm : 0;
    int wblk = (nwt+7)>>3;
    int nproj = (L <= NW-2) ? 384 : 0;
    float* bufR = (L&1) ? compatA : compatB;
    float* bufW = (L&1) ? compatB : compatA;
    k_stage<<<ncomb + wblk + nproj, 512, 0, stream>>>(
        WiBh, WiBl, WsBh, WsBl, WbilTh, WbilTl, bi, bs,
        cHbh, cHbl, cCbh, cCbl, cPI, cPS, cU, cH, cC, cS,
        bufR, bufW, flags, out, L);
  }
}